// Round 1
// baseline (45.683 us; speedup 1.0000x reference)
//
#include <hip/hip_runtime.h>
#include <math.h>

// SPU(x) = x^2 - 0.5 for x >= 0, sigmoid(-x) - 1 for x < 0
__device__ __forceinline__ float spu_f(float x) {
    // sigmoid(-x) - 1 = 1/(1+exp(x)) - 1
    return (x >= 0.0f) ? fmaf(x, x, -0.5f) : (1.0f / (1.0f + expf(x)) - 1.0f);
}

// matches reference spu_grad: 0 for x<=-50, -0.5/(cosh(x)+1) for -50<x<0, 2x for x>=0
__device__ __forceinline__ float spu_grad_f(float x) {
    if (x >= 0.0f) return 2.0f * x;
    if (x <= -50.0f) return 0.0f;
    return -0.5f / (coshf(x) + 1.0f);   // x in (-50, 0): no overflow
}

__device__ __forceinline__ void spu_bounds(float l, float u, float& nl, float& nu) {
    const float sl = spu_f(l);
    const float su = spu_f(u);

    // chord between (l, sl) and (u, su)
    const float a_lu = (su - sl) / (u - l + 1e-8f);
    const float b_lu = sl - l * a_lu;

    // tangent at midpoint
    const float mid = 0.5f * (l + u);
    const float a_t = spu_grad_f(mid);
    const float b_t = spu_f(mid) - a_t * mid;

    const bool neg   = (u < 0.0f);
    const bool pos   = (!neg) && (l > 0.0f);
    const bool mixed = (!neg) && (!pos);
    const bool normal = mixed && (su > sl);

    // mixed lower-bound candidates
    // c1: chord from l to 0 (spu(0) = -0.5)
    const float a1 = (-0.5f - sl) / (-l + 1e-8f);
    const float b1 = sl - l * a1;
    // c2: tangent at u/2
    const float h  = 0.5f * u;
    const float a2 = spu_grad_f(h);
    const float b2 = spu_f(h) - a2 * h;

    // area(a, b) = -(u-l)*(a*(l+u) + 2b)
    const float dlu = u - l;
    const float slu = l + u;
    const float ar0 = dlu;                                  // a=0, b=-0.5
    const float ar1 = -dlu * fmaf(a1, slu, 2.0f * b1);
    const float ar2 = normal ? (-dlu * fmaf(a2, slu, 2.0f * b2)) : INFINITY;

    // argmin over [ar0, ar1, ar2], first-min on ties (jnp.argmin semantics)
    int idx = 0;
    float best = ar0;
    if (ar1 < best) { best = ar1; idx = 1; }
    if (ar2 < best) { idx = 2; }
    const float a_m = (idx == 0) ? 0.0f  : ((idx == 1) ? a1 : a2);
    const float b_m = (idx == 0) ? -0.5f : ((idx == 1) ? b1 : b2);

    const float lw = neg ? a_lu : (pos ? a_t : a_m);
    const float lb = neg ? b_lu : (pos ? b_t : b_m);
    const float uw = neg ? a_t : ((pos || normal) ? a_lu : 0.0f);
    const float ub = neg ? b_t : ((pos || normal) ? b_lu : sl);

    nl = lb + ((lw > 0.0f) ? lw * l : lw * u);
    nu = ub + ((uw > 0.0f) ? uw * u : uw * l);
}

__global__ void __launch_bounds__(256) spu_pointwise_kernel(
        const float* __restrict__ l, const float* __restrict__ u,
        float* __restrict__ out_nl, float* __restrict__ out_nu,
        int n4, int n) {
    const int tid = blockIdx.x * blockDim.x + threadIdx.x;
    const int stride = gridDim.x * blockDim.x;

    const float4* __restrict__ l4 = reinterpret_cast<const float4*>(l);
    const float4* __restrict__ u4 = reinterpret_cast<const float4*>(u);
    float4* __restrict__ nl4 = reinterpret_cast<float4*>(out_nl);
    float4* __restrict__ nu4 = reinterpret_cast<float4*>(out_nu);

    for (int i = tid; i < n4; i += stride) {
        const float4 lv = l4[i];
        const float4 uv = u4[i];
        float4 a, b;
        spu_bounds(lv.x, uv.x, a.x, b.x);
        spu_bounds(lv.y, uv.y, a.y, b.y);
        spu_bounds(lv.z, uv.z, a.z, b.z);
        spu_bounds(lv.w, uv.w, a.w, b.w);
        nl4[i] = a;
        nu4[i] = b;
    }

    // scalar tail (n % 4 != 0) — handled by the first few threads
    const int tail_start = n4 * 4;
    for (int i = tail_start + tid; i < n; i += stride) {
        spu_bounds(l[i], u[i], out_nl[i], out_nu[i]);
    }
}

extern "C" void kernel_launch(void* const* d_in, const int* in_sizes, int n_in,
                              void* d_out, int out_size, void* d_ws, size_t ws_size,
                              hipStream_t stream) {
    const float* l = (const float*)d_in[0];
    const float* u = (const float*)d_in[1];
    float* out = (float*)d_out;

    const int n = in_sizes[0];          // 64 * 65536 = 4194304
    float* out_nl = out;                // first output, flat
    float* out_nu = out + n;            // second output, flat

    const int n4 = n / 4;
    const int block = 256;
    int grid = (n4 + block - 1) / block;
    if (grid > 4096) grid = 4096;       // grid-stride beyond this
    if (grid < 1) grid = 1;

    spu_pointwise_kernel<<<grid, block, 0, stream>>>(l, u, out_nl, out_nu, n4, n);
}

// Round 2
// 17.676 us; speedup vs baseline: 2.5845x; 2.5845x over previous
//
#include <hip/hip_runtime.h>
#include <math.h>

__device__ __forceinline__ float frcp(float x) { return __builtin_amdgcn_rcpf(x); }

// Per-element SPU linear-bound computation, branchless, transcendental-minimized.
// For x < 0:  spu(x) = 1/(1+e^x) - 1,  spu_grad(x) = -e^x/(1+e^x)^2  (== -0.5/(cosh x + 1))
// For x >= 0: spu(x) = x^2 - 0.5,      spu_grad(x) = 2x
__device__ __forceinline__ void spu_bounds(float l, float u, float& nl, float& nu) {
    const float mid = 0.5f * (l + u);

    // one exp per point; shared between value and gradient
    const float e_l = __expf(l);
    const float e_u = __expf(u);
    const float e_m = __expf(mid);
    const float r_l = frcp(1.0f + e_l);
    const float r_u = frcp(1.0f + e_u);
    const float r_m = frcp(1.0f + e_m);

    const float sl = (l   >= 0.0f) ? fmaf(l,   l,   -0.5f) : (r_l - 1.0f);
    const float su = (u   >= 0.0f) ? fmaf(u,   u,   -0.5f) : (r_u - 1.0f);
    const float sm = (mid >= 0.0f) ? fmaf(mid, mid, -0.5f) : (r_m - 1.0f);
    const float gm = (mid >= 0.0f) ? (2.0f * mid)
                   : ((mid <= -50.0f) ? 0.0f : (-e_m * r_m * r_m));

    // chord between (l, sl) and (u, su)
    const float a_lu = (su - sl) * frcp(u - l + 1e-8f);
    const float b_lu = sl - l * a_lu;

    // tangent at midpoint (only consumed when neg or pos)
    const float a_t = gm;
    const float b_t = sm - gm * mid;

    const bool neg    = (u < 0.0f);
    const bool pos    = (!neg) && (l > 0.0f);
    const bool mixed  = (!neg) && (!pos);
    const bool normal = mixed && (su > sl);

    // mixed lower-bound candidates (only consumed when mixed, where l<=0, u>=0)
    // c1: chord from (l, sl) to (0, -0.5)
    const float a1 = (-0.5f - sl) * frcp(1e-8f - l);
    const float b1 = sl - l * a1;
    // c2: tangent at h=u/2 >= 0  ->  a2 = 2h = u,  b2 = (h^2-0.5) - a2*h = -u^2/4 - 0.5
    const float a2 = u;
    const float b2 = -fmaf(0.25f * u, u, 0.5f);

    // area proxy: area(a,b) = -(u-l)*(a*(l+u) + 2b)
    const float dlu = u - l;
    const float slu = u + l;
    const float ar0 = dlu;                                   // a=0, b=-0.5
    const float ar1 = -dlu * fmaf(a1, slu, 2.0f * b1);
    const float ar2 = normal ? (-dlu * fmaf(a2, slu, 2.0f * b2)) : INFINITY;

    // argmin over [ar0, ar1, ar2], first-min on ties (jnp.argmin semantics)
    int idx = 0;
    float best = ar0;
    if (ar1 < best) { best = ar1; idx = 1; }
    if (ar2 < best) { idx = 2; }
    const float a_m = (idx == 0) ? 0.0f  : ((idx == 1) ? a1 : a2);
    const float b_m = (idx == 0) ? -0.5f : ((idx == 1) ? b1 : b2);

    const float lw = neg ? a_lu : (pos ? a_t : a_m);
    const float lb = neg ? b_lu : (pos ? b_t : b_m);
    const float uw = neg ? a_t : ((pos || normal) ? a_lu : 0.0f);
    const float ub = neg ? b_t : ((pos || normal) ? b_lu : sl);

    nl = lb + ((lw > 0.0f) ? lw * l : lw * u);
    nu = ub + ((uw > 0.0f) ? uw * u : uw * l);
}

__global__ void __launch_bounds__(256) spu_pointwise_kernel(
        const float* __restrict__ l, const float* __restrict__ u,
        float* __restrict__ out_nl, float* __restrict__ out_nu,
        int n4, int n) {
    const int tid = blockIdx.x * blockDim.x + threadIdx.x;
    const int stride = gridDim.x * blockDim.x;

    const float4* __restrict__ l4 = reinterpret_cast<const float4*>(l);
    const float4* __restrict__ u4 = reinterpret_cast<const float4*>(u);
    float4* __restrict__ nl4 = reinterpret_cast<float4*>(out_nl);
    float4* __restrict__ nu4 = reinterpret_cast<float4*>(out_nu);

    for (int i = tid; i < n4; i += stride) {
        const float4 lv = l4[i];
        const float4 uv = u4[i];
        float4 a, b;
        spu_bounds(lv.x, uv.x, a.x, b.x);
        spu_bounds(lv.y, uv.y, a.y, b.y);
        spu_bounds(lv.z, uv.z, a.z, b.z);
        spu_bounds(lv.w, uv.w, a.w, b.w);
        nl4[i] = a;
        nu4[i] = b;
    }

    // scalar tail (n % 4 != 0)
    const int tail_start = n4 * 4;
    for (int i = tail_start + tid; i < n; i += stride) {
        spu_bounds(l[i], u[i], out_nl[i], out_nu[i]);
    }
}

extern "C" void kernel_launch(void* const* d_in, const int* in_sizes, int n_in,
                              void* d_out, int out_size, void* d_ws, size_t ws_size,
                              hipStream_t stream) {
    const float* l = (const float*)d_in[0];
    const float* u = (const float*)d_in[1];
    float* out = (float*)d_out;

    const int n = in_sizes[0];          // 64 * 65536 = 4194304
    float* out_nl = out;                // first output, flat
    float* out_nu = out + n;            // second output, flat

    const int n4 = n / 4;
    const int block = 256;
    int grid = (n4 + block - 1) / block;
    if (grid > 4096) grid = 4096;       // grid-stride beyond this
    if (grid < 1) grid = 1;

    spu_pointwise_kernel<<<grid, block, 0, stream>>>(l, u, out_nl, out_nu, n4, n);
}